// Round 6
// baseline (488.077 us; speedup 1.0000x reference)
//
#include <hip/hip_runtime.h>
#include <hip/hip_bf16.h>
#include <stdint.h>
#include <math.h>

#define H_ 16
#define HD_ 128
#define RD_ 64
#define CD_ 64
#define DM_ 2048
#define QR_ 512
#define DL_ 512
#define B_ 2
#define T_ 2048
#define M_TOT (B_*T_)

typedef __attribute__((ext_vector_type(8))) short short8;
typedef __attribute__((ext_vector_type(4))) float f32x4;
typedef __attribute__((ext_vector_type(16))) float f32x16;

__device__ __forceinline__ unsigned short f2b_hw(float f){
  __hip_bfloat16 h = __float2bfloat16(f);
  union { __hip_bfloat16 h; unsigned short u; } c; c.h = h; return c.u;
}
__device__ __forceinline__ float b2f(unsigned short b){
  union { unsigned u; float f; } a; a.u = ((unsigned)b) << 16;
  return a.f;
}
__device__ __forceinline__ unsigned pack2(float lo, float hi){
  __hip_bfloat162 h2 = __float22bfloat162_rn(make_float2(lo, hi));
  union { __hip_bfloat162 h; unsigned u; } c; c.h = h2; return c.u;
}

#define GLOAD16(g, l) __builtin_amdgcn_global_load_lds( \
    (__attribute__((address_space(1))) void*)(g), \
    (__attribute__((address_space(3))) void*)(l), 16, 0, 0)

// ---------------- cast f32 -> bf16 ----------------
__global__ void cast_f32_bf16(const float* __restrict__ src,
                              unsigned short* __restrict__ dst, int n){
  int i = (blockIdx.x * blockDim.x + threadIdx.x) * 4;
  if (i < n){
    float4 v = *(const float4*)(src + i);
    ushort4 o;
    o.x = f2b_hw(v.x); o.y = f2b_hw(v.y); o.z = f2b_hw(v.z); o.w = f2b_hw(v.w);
    *(ushort4*)(dst + i) = o;
  }
}

// ---------------- combined transpose+cast for all 8 weights ----------------
struct TTe { const float* src; unsigned short* dst; int K, N, blk0; };
struct TT8 { TTe e[8]; };

__global__ void transpose_cast8(TT8 tab){
  __shared__ float tile[32][33];
  int bid = blockIdx.x;
  const float* src = tab.e[0].src;
  unsigned short* dst = tab.e[0].dst;
  int K = tab.e[0].K, N = tab.e[0].N, loc = bid;
  #pragma unroll
  for (int j = 1; j < 8; j++){
    if (bid >= tab.e[j].blk0){
      src = tab.e[j].src; dst = tab.e[j].dst;
      K = tab.e[j].K; N = tab.e[j].N; loc = bid - tab.e[j].blk0;
    }
  }
  int cols = N / 32;
  int n0 = (loc % cols) * 32, k0 = (loc / cols) * 32;
  int tx = threadIdx.x, ty = threadIdx.y; // (32,8)
  #pragma unroll
  for (int r = ty; r < 32; r += 8)
    tile[r][tx] = src[(size_t)(k0 + r) * N + n0 + tx];
  __syncthreads();
  #pragma unroll
  for (int r = ty; r < 32; r += 8)
    dst[(size_t)(n0 + r) * K + k0 + tx] = f2b_hw(tile[tx][r]);
}

// ---------------- GEMM: modes 0=bf16 linear, 1=f32 linear, 2=qh scatter, 3=kh+vt scatter --------
template<int MODE>
__global__ __launch_bounds__(256) void gemm_bt(
    const unsigned short* __restrict__ A, int lda,
    const unsigned short* __restrict__ Bt,
    void* __restrict__ Cv, void* __restrict__ Cv2, int ldc, int N, int K)
{
  __shared__ unsigned short As[128 * 32];
  __shared__ unsigned short Bs[128 * 32];
  int tid = threadIdx.x;

  int gx = gridDim.x;
  int nwg = gx * gridDim.y;
  int lin = blockIdx.x + gx * blockIdx.y;
  int q8 = nwg >> 3;
  int nl = (lin & 7) * q8 + (lin >> 3);
  int m0 = (nl / gx) * 128, n0 = (nl % gx) * 128;

  int lane = tid & 63, w = tid >> 6;
  int wr = (w >> 1) * 64, wc = (w & 1) * 64;
  int mr = lane & 15, kg = lane >> 4;

  const unsigned short* Ag = A  + (size_t)(m0 + (tid >> 2)) * lda + ((tid & 3) << 3);
  const unsigned short* Bg = Bt + (size_t)(n0 + (tid >> 2)) * K + ((tid & 3) << 3);

  f32x4 acc[4][4];
  #pragma unroll
  for (int i = 0; i < 4; i++)
    #pragma unroll
    for (int j = 0; j < 4; j++)
      acc[i][j] = (f32x4){0.f, 0.f, 0.f, 0.f};

  for (int k0 = 0; k0 < K; k0 += 32) {
    #pragma unroll
    for (int j = 0; j < 2; j++) {
      GLOAD16(Ag + (size_t)j * 64 * lda, &As[j * 2048 + tid * 8]);
      GLOAD16(Bg + (size_t)j * 64 * K, &Bs[j * 2048 + tid * 8]);
    }
    Ag += 32; Bg += 32;
    __syncthreads();
    short8 af[4], bf[4];
    #pragma unroll
    for (int i = 0; i < 4; i++)
      af[i] = *(const short8*)&As[(wr + i * 16 + mr) * 32 + kg * 8];
    #pragma unroll
    for (int j = 0; j < 4; j++)
      bf[j] = *(const short8*)&Bs[(wc + j * 16 + mr) * 32 + kg * 8];
    __builtin_amdgcn_s_setprio(1);
    #pragma unroll
    for (int i = 0; i < 4; i++)
      #pragma unroll
      for (int j = 0; j < 4; j++)
        acc[i][j] = __builtin_amdgcn_mfma_f32_16x16x32_bf16(af[i], bf[j], acc[i][j], 0, 0, 0);
    __builtin_amdgcn_s_setprio(0);
    __syncthreads();
  }

  if (MODE == 1) {
    float* C = (float*)Cv;
    #pragma unroll
    for (int i = 0; i < 4; i++)
      #pragma unroll
      for (int j = 0; j < 4; j++)
        #pragma unroll
        for (int r = 0; r < 4; r++) {
          int row = m0 + wr + i * 16 + kg * 4 + r;
          int col = n0 + wc + j * 16 + mr;
          C[(size_t)row * ldc + col] = acc[i][j][r];
        }
  } else if (MODE == 0) {
    unsigned short* C = (unsigned short*)Cv;
    #pragma unroll
    for (int i = 0; i < 4; i++)
      #pragma unroll
      for (int j = 0; j < 4; j++)
        #pragma unroll
        for (int r = 0; r < 4; r++) {
          int row = m0 + wr + i * 16 + kg * 4 + r;
          int col = n0 + wc + j * 16 + mr;
          C[(size_t)row * ldc + col] = f2b_hw(acc[i][j][r]);
        }
  } else if (MODE == 2) {
    // scatter to qh[B,H,T,128], content half: col -> h=col>>6, d=col&63
    unsigned short* qhp = (unsigned short*)Cv;
    #pragma unroll
    for (int i = 0; i < 4; i++)
      #pragma unroll
      for (int j = 0; j < 4; j++) {
        int colb = n0 + wc + j * 16 + mr;
        int h = colb >> 6, d = colb & 63;
        #pragma unroll
        for (int r = 0; r < 4; r++) {
          int gr = m0 + wr + i * 16 + kg * 4 + r;
          size_t idx = ((size_t)((gr >> 11) * H_ + h) * T_ + (gr & (T_-1))) * 128 + d;
          qhp[idx] = f2b_hw(acc[i][j][r]);
        }
      }
  } else { // MODE 3: cols<1024 -> kh content; cols>=1024 -> vt transposed
    unsigned short* khp = (unsigned short*)Cv;
    unsigned short* vtp = (unsigned short*)Cv2;
    if (n0 < 1024) {
      #pragma unroll
      for (int i = 0; i < 4; i++)
        #pragma unroll
        for (int j = 0; j < 4; j++) {
          int colb = n0 + wc + j * 16 + mr;
          int h = colb >> 6, d = colb & 63;
          #pragma unroll
          for (int r = 0; r < 4; r++) {
            int gr = m0 + wr + i * 16 + kg * 4 + r;
            size_t idx = ((size_t)((gr >> 11) * H_ + h) * T_ + (gr & (T_-1))) * 128 + d;
            khp[idx] = f2b_hw(acc[i][j][r]);
          }
        }
    } else {
      #pragma unroll
      for (int i = 0; i < 4; i++)
        #pragma unroll
        for (int j = 0; j < 4; j++) {
          int c2 = n0 + wc + j * 16 + mr - 1024;
          int h = c2 >> 7, d = c2 & 127;
          int gr0 = m0 + wr + i * 16 + kg * 4;
          int b = gr0 >> 11, t0 = gr0 & (T_-1);
          ushort4 o;
          o.x = f2b_hw(acc[i][j][0]); o.y = f2b_hw(acc[i][j][1]);
          o.z = f2b_hw(acc[i][j][2]); o.w = f2b_hw(acc[i][j][3]);
          size_t idx = ((size_t)(b * H_ + h) * 128 + d) * T_ + t0;
          *(ushort4*)&vtp[idx] = o;
        }
    }
  }
}

// ---------------- rope-only: fill qh/kh d=64..127 ----------------
// projall: qp at col 1024, kp at col 2048, ld 3072
__global__ void rope_fill(const unsigned short* __restrict__ projall,
                          unsigned short* __restrict__ qh,
                          unsigned short* __restrict__ kh){
  int row = blockIdx.x * 8 + threadIdx.y;   // (bh,t) flattened
  int j = threadIdx.x;                      // 0..31
  int bh = row >> 11;
  int t  = row & (T_ - 1);
  int b = bh >> 4, h = bh & 15;
  size_t srow = (size_t)b * T_ + t;
  const unsigned short* qp = projall + srow * 3072 + 1024 + h * 64;
  const unsigned short* kp = qp + 1024;
  float invf = exp2f(-(float)j * 0.4152410118750f);
  float f = (float)t * invf;
  float s, c;
  sincosf(f, &s, &c);
  float qx1 = b2f(qp[j]), qx2 = b2f(qp[j + 32]);
  float kx1 = b2f(kp[j]), kx2 = b2f(kp[j + 32]);
  size_t dst = ((size_t)bh * T_ + t) * 128 + 64;
  qh[dst + j]      = f2b_hw(qx1 * c - qx2 * s);
  qh[dst + j + 32] = f2b_hw(qx1 * s + qx2 * c);
  kh[dst + j]      = f2b_hw(kx1 * c - kx2 * s);
  kh[dst + j + 32] = f2b_hw(kx1 * s + kx2 * c);
}

// ---------------- causal flash attention: K dbuf + V single-buffer, 48KB LDS ----------------
__global__ __launch_bounds__(256, 3) void attn_fwd4(
    const unsigned short* __restrict__ qh,
    const unsigned short* __restrict__ kh,
    const unsigned short* __restrict__ vt,
    unsigned short* __restrict__ ao)
{
  // flat LDS, manual partition: Ks[2][64*128] | Vs[128*64]  = 48KB
  __shared__ __align__(16) unsigned short lds[3 * 8192];
  unsigned short* const Vsp = lds + 16384;

  const int tid  = threadIdx.x;
  const int lane = tid & 63, w = tid >> 6;
  const int l31  = lane & 31, hi = lane >> 5;
  const int bh = blockIdx.y;
  const int b  = bh >> 4, hd = bh & 15;
  int qt = blockIdx.x;
  if (blockIdx.y >= 16) qt = 15 - qt;            // pair long+short tiles per CU
  const int q0    = qt * 128;
  const int q0w   = q0 + w * 32;
  const int qg    = q0w + l31;
  const int qmaxw = q0w + 31;
  const int nt    = 2 * qt + 2;

  const unsigned short* Qg = qh + (size_t)bh * T_ * 128;
  const unsigned short* Kg = kh + (size_t)bh * T_ * 128;
  const unsigned short* Vg = vt + (size_t)bh * 128 * T_;

  short8 qf[8];
  #pragma unroll
  for (int kc = 0; kc < 8; kc++)
    qf[kc] = *(const short8*)&Qg[(size_t)qg * 128 + kc * 16 + hi * 8];

  f32x16 accO[4];
  #pragma unroll
  for (int sb = 0; sb < 4; sb++)
    #pragma unroll
    for (int r = 0; r < 16; r++) accO[sb][r] = 0.f;

  float m = -1e30f, lsum = 0.f;
  const float SC = 0.12751743f;   // (1/sqrt(128)) * log2(e)

  // staging coordinates (per wave: 4 K rows + 4 V rows, 16B per lane)
  int krow[4], kwof[4], vrow[4], vwof[4];
  #pragma unroll
  for (int j = 0; j < 4; j++){
    int r_ = (w * 4 + j) * 4 + (lane >> 4);
    krow[j] = r_;
    kwof[j] = r_ * 128 + ((((lane & 15) * 16) ^ ((r_ & 7) << 4)) >> 1);
    int d_ = (w * 4 + j) * 8 + (lane >> 3);
    vrow[j] = d_;
    vwof[j] = d_ * 64 + ((((lane & 7) * 16) ^ ((d_ & 7) << 4)) >> 1);
  }
  const int kcol = (lane & 15) * 8;
  const int vcol = (lane & 7) * 8;

  uint4 kst[4], vst[4];

#define REG_LOAD_K(kvt) do {                                                  \
    int kv0s = (kvt) * 64;                                                    \
    _Pragma("unroll")                                                         \
    for (int j_ = 0; j_ < 4; j_++)                                            \
      kst[j_] = *(const uint4*)&Kg[(size_t)(kv0s + krow[j_]) * 128 + kcol];   \
  } while (0)
#define REG_LOAD_V(kvt) do {                                                  \
    int kv0s = (kvt) * 64;                                                    \
    _Pragma("unroll")                                                         \
    for (int j_ = 0; j_ < 4; j_++)                                            \
      vst[j_] = *(const uint4*)&Vg[(size_t)vrow[j_] * T_ + kv0s + vcol];      \
  } while (0)
#define DS_WRITE_K(bufi) do {                                                 \
    unsigned short* ksb_ = lds + (bufi) * 8192;                               \
    _Pragma("unroll")                                                         \
    for (int j_ = 0; j_ < 4; j_++)                                            \
      *(uint4*)&ksb_[kwof[j_]] = kst[j_];                                     \
  } while (0)
#define DS_WRITE_V() do {                                                     \
    _Pragma("unroll")                                                         \
    for (int j_ = 0; j_ < 4; j_++)                                            \
      *(uint4*)&Vsp[vwof[j_]] = vst[j_];                                      \
  } while (0)

  // prologue: K0 -> LDS buf0; V0 -> regs; K1 -> regs (no barrier needed yet)
  REG_LOAD_K(0);
  REG_LOAD_V(0);
  DS_WRITE_K(0);
  if (nt > 1) REG_LOAD_K(1);

  for (int t = 0; t < nt; t++) {
    const int cur = t & 1;
    DS_WRITE_V();                        // V(t): Vs free (barrier#2 of t-1)
    if (t + 1 < nt) DS_WRITE_K(cur ^ 1); // K(t+1)
    if (t + 1 < nt) REG_LOAD_V(t + 1);
    if (t + 2 < nt) REG_LOAD_K(t + 2);
    __builtin_amdgcn_sched_barrier(0);
    asm volatile("s_waitcnt lgkmcnt(0)" ::: "memory");
    __builtin_amdgcn_s_barrier();        // barrier#1: Vs=V(t), Ks[cur]=K(t) visible
    __builtin_amdgcn_sched_barrier(0);

    if (t * 64 <= qmaxw) {
      const int kv0 = t * 64;
      const unsigned short* Kb = lds + cur * 8192;

      // ---- QK^T (swapped): S^T[kv][q], lane owns q col ----
      f32x16 sa0, sa1;
      #pragma unroll
      for (int r = 0; r < 16; r++) { sa0[r] = 0.f; sa1[r] = 0.f; }
      __builtin_amdgcn_s_setprio(1);
      #pragma unroll
      for (int kc = 0; kc < 8; kc++) {
        int co = (kc * 32 + hi * 16);
        int r0 = l31;
        short8 kf0 = *(const short8*)&Kb[r0 * 128 + ((co ^ ((r0 & 7) << 4)) >> 1)];
        sa0 = __builtin_amdgcn_mfma_f32_32x32x16_bf16(kf0, qf[kc], sa0, 0, 0, 0);
        int r1 = 32 + l31;
        short8 kf1 = *(const short8*)&Kb[r1 * 128 + ((co ^ ((r1 & 7) << 4)) >> 1)];
        sa1 = __builtin_amdgcn_mfma_f32_32x32x16_bf16(kf1, qf[kc], sa1, 0, 0, 0);
      }
      __builtin_amdgcn_s_setprio(0);

      // ---- lane-local softmax (exp2 domain) ----
      float p0[16], p1[16];
      float pmax = -1e30f;
      bool needMask = (kv0 + 63 > q0w);
      if (needMask) {
        #pragma unroll
        for (int r = 0; r < 16; r++) {
          int crow = (r & 3) + 8 * (r >> 2) + 4 * hi;
          float v0 = sa0[r] * SC;
          float v1 = sa1[r] * SC;
          if (kv0 + crow > qg)      v0 = -1e30f;
          if (kv0 + 32 + crow > qg) v1 = -1e30f;
          p0[r] = v0; p1[r] = v1;
          pmax = fmaxf(pmax, fmaxf(v0, v1));
        }
      } else {
        #pragma unroll
        for (int r = 0; r < 16; r++) {
          float v0 = sa0[r] * SC;
          float v1 = sa1[r] * SC;
          p0[r] = v0; p1[r] = v1;
          pmax = fmaxf(pmax, fmaxf(v0, v1));
        }
      }
      pmax = fmaxf(pmax, __shfl_xor(pmax, 32, 64));
      if (!__all(pmax <= m + 8.f)) {     // T13 defer-max
        float mn  = fmaxf(m, pmax);
        float fac = exp2f(m - mn);
        m = mn;
        lsum *= fac;
        #pragma unroll
        for (int sb = 0; sb < 4; sb++)
          #pragma unroll
          for (int r = 0; r < 16; r++) accO[sb][r] *= fac;
      }
      float ls = 0.f;
      #pragma unroll
      for (int r = 0; r < 16; r++) {
        p0[r] = exp2f(p0[r] - m);
        p1[r] = exp2f(p1[r] - m);
        ls += p0[r] + p1[r];
      }
      ls += __shfl_xor(ls, 32, 64);
      lsum += ls;

      // ---- PV: O^T[d][q] += V^T-frag x P-frag (pa via permlane32_swap, T12) ----
      #pragma unroll
      for (int kc2 = 0; kc2 < 4; kc2++) {
        unsigned A01, A23, B01, B23;
        if (kc2 == 0) { A01 = pack2(p0[0], p0[1]);  A23 = pack2(p0[2], p0[3]);
                        B01 = pack2(p0[4], p0[5]);  B23 = pack2(p0[6], p0[7]); }
        else if (kc2 == 1) { A01 = pack2(p0[8], p0[9]);   A23 = pack2(p0[10], p0[11]);
                             B01 = pack2(p0[12], p0[13]); B23 = pack2(p0[14], p0[15]); }
        else if (kc2 == 2) { A01 = pack2(p1[0], p1[1]);  A23 = pack2(p1[2], p1[3]);
                             B01 = pack2(p1[4], p1[5]);  B23 = pack2(p1[6], p1[7]); }
        else { A01 = pack2(p1[8], p1[9]);   A23 = pack2(p1[10], p1[11]);
               B01 = pack2(p1[12], p1[13]); B23 = pack2(p1[14], p1[15]); }
        // D = {D_lo, S_lo}, S = {D_hi, S_hi}
        asm("v_permlane32_swap_b32 %0, %1" : "+v"(A01), "+v"(B01));
        asm("v_permlane32_swap_b32 %0, %1" : "+v"(A23), "+v"(B23));
        union { unsigned u[4]; short8 v; } pk;
        pk.u[0] = A01; pk.u[1] = A23; pk.u[2] = B01; pk.u[3] = B23;
        short8 pa = pk.v;
        __builtin_amdgcn_s_setprio(1);
        #pragma unroll
        for (int sb = 0; sb < 4; sb++) {
          int d = sb * 32 + l31;
          short8 vf = *(const short8*)&Vsp[d * 64 + (((kc2 * 32 + hi * 16) ^ ((d & 7) << 4)) >> 1)];
          accO[sb] = __builtin_amdgcn_mfma_f32_32x32x16_bf16(vf, pa, accO[sb], 0, 0, 0);
        }
        __builtin_amdgcn_s_setprio(0);
      }
    }
    __builtin_amdgcn_sched_barrier(0);
    asm volatile("s_waitcnt lgkmcnt(0)" ::: "memory");
    __builtin_amdgcn_s_barrier();        // barrier#2: reads of Vs/Ks done -> next iter may write
    __builtin_amdgcn_sched_barrier(0);
  }

  float rl = 1.0f / lsum;
  size_t orow = ((size_t)b * T_ + qg) * (H_*HD_) + hd * 128;
  #pragma unroll
  for (int sb = 0; sb < 4; sb++)
    #pragma unroll
    for (int g = 0; g < 4; g++) {
      ushort4 o;
      o.x = f2b_hw(accO[sb][4 * g + 0] * rl);
      o.y = f2b_hw(accO[sb][4 * g + 1] * rl);
      o.z = f2b_hw(accO[sb][4 * g + 2] * rl);
      o.w = f2b_hw(accO[sb][4 * g + 3] * rl);
      *(ushort4*)&ao[orow + sb * 32 + 8 * g + 4 * hi] = o;
    }
#undef REG_LOAD_K
#undef REG_LOAD_V
#undef DS_WRITE_K
#undef DS_WRITE_V
}

// ---------------- launcher ----------------
extern "C" void kernel_launch(void* const* d_in, const int* in_sizes, int n_in,
                              void* d_out, int out_size, void* d_ws, size_t ws_size,
                              hipStream_t stream)
{
  (void)in_sizes; (void)n_in; (void)out_size; (void)ws_size;
  const float* x        = (const float*)d_in[0];
  const float* Wq_down  = (const float*)d_in[1];
  const float* Wq_up    = (const float*)d_in[2];
  const float* Wq_rope  = (const float*)d_in[3];
  const float* Wkv_down = (const float*)d_in[4];
  const float* Wk_up    = (const float*)d_in[5];
  const float* Wv_up    = (const float*)d_in[6];
  const float* Wk_rope  = (const float*)d_in[7];
  const float* Wo       = (const float*)d_in[8];

  char* ws = (char*)d_ws;
  unsigned short* xb      = (unsigned short*)(ws + 0);          // [4096,2048] 16 MB
  unsigned short* Wdall   = (unsigned short*)(ws + 16777216);   // [3072,2048] 12 MB
  unsigned short* WquT    = (unsigned short*)(ws + 29360128);   // [1024,512]  1 MB
  unsigned short* WkcvT   = (unsigned short*)(ws + 30408704);   // [3072,512]  3 MB
  unsigned short* WoT     = (unsigned short*)(ws + 33554432);   // [2048,2048] 8 MB
  unsigned short* projall = (unsigned short*)(ws + 41943040);   // [4096,3072] 24 MB (lat|qp|kp); reused as ao
  unsigned short* qh      = (unsigned short*)(ws + 67108864);   // [B,H,T,128] 16 MB
  unsigned short* kh      = (unsigned short*)(ws + 83886080);   // 16 MB
  unsigned short* vt      = (unsigned short*)(ws + 100663296);  // [B,H,128,T] 16 MB
  unsigned short* ao      = projall;  // projall dead after rope_fill

  dim3 tb(32, 8);

  cast_f32_bf16<<<(M_TOT * DM_ / 4 + 255) / 256, 256, 0, stream>>>(x, xb, M_TOT * DM_);

  TT8 tab;
  int blk = 0;
  tab.e[0] = { Wq_down,  Wdall,               DM_, QR_,     blk }; blk += (QR_/32)*(DM_/32);
  tab.e[1] = { Wkv_down, Wdall + 512*2048,    DM_, DL_,     blk }; blk += (DL_/32)*(DM_/32);
  tab.e[2] = { Wq_rope,  Wdall + 1024*2048,   DM_, H_*RD_,  blk }; blk += (H_*RD_/32)*(DM_/32);
  tab.e[3] = { Wk_rope,  Wdall + 2048*2048,   DM_, H_*RD_,  blk }; blk += (H_*RD_/32)*(DM_/32);
  tab.e[4] = { Wq_up,    WquT,                QR_, H_*CD_,  blk }; blk += (H_*CD_/32)*(QR_/32);
  tab.e[5] = { Wk_up,    WkcvT,               DL_, H_*CD_,  blk }; blk += (H_*CD_/32)*(DL_/32);
  tab.e[6] = { Wv_up,    WkcvT + 1024*512,    DL_, H_*HD_,  blk }; blk += (H_*HD_/32)*(DL_/32);
  tab.e[7] = { Wo,       WoT,                 H_*HD_, DM_,  blk }; blk += (DM_/32)*(H_*HD_/32);
  transpose_cast8<<<blk, tb, 0, stream>>>(tab);

  // down+rope projections in one N=3072 GEMM -> projall
  gemm_bt<0><<<dim3(3072/128, M_TOT/128), 256, 0, stream>>>(xb, DM_, Wdall, projall, nullptr, 3072, 3072, DM_);
  // q-up: writes qh content half directly
  gemm_bt<2><<<dim3(1024/128, M_TOT/128), 256, 0, stream>>>(projall, 3072, WquT, qh, nullptr, 0, 1024, QR_);
  // k-up + v-up: writes kh content half + vt (transposed) directly
  gemm_bt<3><<<dim3(3072/128, M_TOT/128), 256, 0, stream>>>(projall + 512, 3072, WkcvT, kh, vt, 0, 3072, DL_);
  // rope halves of qh/kh
  rope_fill<<<dim3(B_*H_*T_/8), dim3(32, 8), 0, stream>>>(projall, qh, kh);

  attn_fwd4<<<dim3(16, 32), 256, 0, stream>>>(qh, kh, vt, ao);

  gemm_bt<1><<<dim3(DM_/128, M_TOT/128), 256, 0, stream>>>(ao, 2048, WoT, d_out, nullptr, DM_, DM_, H_*HD_);
}

// Round 7
// 341.485 us; speedup vs baseline: 1.4293x; 1.4293x over previous
//
#include <hip/hip_runtime.h>
#include <hip/hip_bf16.h>
#include <stdint.h>
#include <math.h>

#define H_ 16
#define HD_ 128
#define RD_ 64
#define CD_ 64
#define DM_ 2048
#define QR_ 512
#define DL_ 512
#define B_ 2
#define T_ 2048
#define M_TOT (B_*T_)

typedef __attribute__((ext_vector_type(8))) short short8;
typedef __attribute__((ext_vector_type(4))) float f32x4;
typedef __attribute__((ext_vector_type(16))) float f32x16;

__device__ __forceinline__ unsigned short f2b_hw(float f){
  __hip_bfloat16 h = __float2bfloat16(f);
  union { __hip_bfloat16 h; unsigned short u; } c; c.h = h; return c.u;
}
__device__ __forceinline__ float b2f(unsigned short b){
  union { unsigned u; float f; } a; a.u = ((unsigned)b) << 16;
  return a.f;
}
__device__ __forceinline__ unsigned pack2(float lo, float hi){
  __hip_bfloat162 h2 = __float22bfloat162_rn(make_float2(lo, hi));
  union { __hip_bfloat162 h; unsigned u; } c; c.h = h2; return c.u;
}

#define GLOAD16(g, l) __builtin_amdgcn_global_load_lds( \
    (__attribute__((address_space(1))) void*)(g), \
    (__attribute__((address_space(3))) void*)(l), 16, 0, 0)

// ---------------- cast f32 -> bf16 ----------------
__global__ void cast_f32_bf16(const float* __restrict__ src,
                              unsigned short* __restrict__ dst, int n){
  int i = (blockIdx.x * blockDim.x + threadIdx.x) * 4;
  if (i < n){
    float4 v = *(const float4*)(src + i);
    ushort4 o;
    o.x = f2b_hw(v.x); o.y = f2b_hw(v.y); o.z = f2b_hw(v.z); o.w = f2b_hw(v.w);
    *(ushort4*)(dst + i) = o;
  }
}

// ---------------- combined transpose+cast for all 8 weights ----------------
struct TTe { const float* src; unsigned short* dst; int K, N, blk0; };
struct TT8 { TTe e[8]; };

__global__ void transpose_cast8(TT8 tab){
  __shared__ float tile[32][33];
  int bid = blockIdx.x;
  const float* src = tab.e[0].src;
  unsigned short* dst = tab.e[0].dst;
  int K = tab.e[0].K, N = tab.e[0].N, loc = bid;
  #pragma unroll
  for (int j = 1; j < 8; j++){
    if (bid >= tab.e[j].blk0){
      src = tab.e[j].src; dst = tab.e[j].dst;
      K = tab.e[j].K; N = tab.e[j].N; loc = bid - tab.e[j].blk0;
    }
  }
  int cols = N / 32;
  int n0 = (loc % cols) * 32, k0 = (loc / cols) * 32;
  int tx = threadIdx.x, ty = threadIdx.y; // (32,8)
  #pragma unroll
  for (int r = ty; r < 32; r += 8)
    tile[r][tx] = src[(size_t)(k0 + r) * N + n0 + tx];
  __syncthreads();
  #pragma unroll
  for (int r = ty; r < 32; r += 8)
    dst[(size_t)(n0 + r) * K + k0 + tx] = f2b_hw(tile[tx][r]);
}

// ---------------- GEMM: modes 0=bf16 linear, 1=f32 linear, 2=qh scatter, 3=kh+vt scatter --------
template<int MODE>
__global__ __launch_bounds__(256) void gemm_bt(
    const unsigned short* __restrict__ A, int lda,
    const unsigned short* __restrict__ Bt,
    void* __restrict__ Cv, void* __restrict__ Cv2, int ldc, int N, int K)
{
  __shared__ unsigned short As[128 * 32];
  __shared__ unsigned short Bs[128 * 32];
  int tid = threadIdx.x;

  int gx = gridDim.x;
  int nwg = gx * gridDim.y;
  int lin = blockIdx.x + gx * blockIdx.y;
  int q8 = nwg >> 3;
  int nl = (lin & 7) * q8 + (lin >> 3);
  int m0 = (nl / gx) * 128, n0 = (nl % gx) * 128;

  int lane = tid & 63, w = tid >> 6;
  int wr = (w >> 1) * 64, wc = (w & 1) * 64;
  int mr = lane & 15, kg = lane >> 4;

  const unsigned short* Ag = A  + (size_t)(m0 + (tid >> 2)) * lda + ((tid & 3) << 3);
  const unsigned short* Bg = Bt + (size_t)(n0 + (tid >> 2)) * K + ((tid & 3) << 3);

  f32x4 acc[4][4];
  #pragma unroll
  for (int i = 0; i < 4; i++)
    #pragma unroll
    for (int j = 0; j < 4; j++)
      acc[i][j] = (f32x4){0.f, 0.f, 0.f, 0.f};

  for (int k0 = 0; k0 < K; k0 += 32) {
    #pragma unroll
    for (int j = 0; j < 2; j++) {
      GLOAD16(Ag + (size_t)j * 64 * lda, &As[j * 2048 + tid * 8]);
      GLOAD16(Bg + (size_t)j * 64 * K, &Bs[j * 2048 + tid * 8]);
    }
    Ag += 32; Bg += 32;
    __syncthreads();
    short8 af[4], bf[4];
    #pragma unroll
    for (int i = 0; i < 4; i++)
      af[i] = *(const short8*)&As[(wr + i * 16 + mr) * 32 + kg * 8];
    #pragma unroll
    for (int j = 0; j < 4; j++)
      bf[j] = *(const short8*)&Bs[(wc + j * 16 + mr) * 32 + kg * 8];
    __builtin_amdgcn_s_setprio(1);
    #pragma unroll
    for (int i = 0; i < 4; i++)
      #pragma unroll
      for (int j = 0; j < 4; j++)
        acc[i][j] = __builtin_amdgcn_mfma_f32_16x16x32_bf16(af[i], bf[j], acc[i][j], 0, 0, 0);
    __builtin_amdgcn_s_setprio(0);
    __syncthreads();
  }

  if (MODE == 1) {
    float* C = (float*)Cv;
    #pragma unroll
    for (int i = 0; i < 4; i++)
      #pragma unroll
      for (int j = 0; j < 4; j++)
        #pragma unroll
        for (int r = 0; r < 4; r++) {
          int row = m0 + wr + i * 16 + kg * 4 + r;
          int col = n0 + wc + j * 16 + mr;
          C[(size_t)row * ldc + col] = acc[i][j][r];
        }
  } else if (MODE == 0) {
    unsigned short* C = (unsigned short*)Cv;
    #pragma unroll
    for (int i = 0; i < 4; i++)
      #pragma unroll
      for (int j = 0; j < 4; j++)
        #pragma unroll
        for (int r = 0; r < 4; r++) {
          int row = m0 + wr + i * 16 + kg * 4 + r;
          int col = n0 + wc + j * 16 + mr;
          C[(size_t)row * ldc + col] = f2b_hw(acc[i][j][r]);
        }
  } else if (MODE == 2) {
    unsigned short* qhp = (unsigned short*)Cv;
    #pragma unroll
    for (int i = 0; i < 4; i++)
      #pragma unroll
      for (int j = 0; j < 4; j++) {
        int colb = n0 + wc + j * 16 + mr;
        int h = colb >> 6, d = colb & 63;
        #pragma unroll
        for (int r = 0; r < 4; r++) {
          int gr = m0 + wr + i * 16 + kg * 4 + r;
          size_t idx = ((size_t)((gr >> 11) * H_ + h) * T_ + (gr & (T_-1))) * 128 + d;
          qhp[idx] = f2b_hw(acc[i][j][r]);
        }
      }
  } else { // MODE 3
    unsigned short* khp = (unsigned short*)Cv;
    unsigned short* vtp = (unsigned short*)Cv2;
    if (n0 < 1024) {
      #pragma unroll
      for (int i = 0; i < 4; i++)
        #pragma unroll
        for (int j = 0; j < 4; j++) {
          int colb = n0 + wc + j * 16 + mr;
          int h = colb >> 6, d = colb & 63;
          #pragma unroll
          for (int r = 0; r < 4; r++) {
            int gr = m0 + wr + i * 16 + kg * 4 + r;
            size_t idx = ((size_t)((gr >> 11) * H_ + h) * T_ + (gr & (T_-1))) * 128 + d;
            khp[idx] = f2b_hw(acc[i][j][r]);
          }
        }
    } else {
      #pragma unroll
      for (int i = 0; i < 4; i++)
        #pragma unroll
        for (int j = 0; j < 4; j++) {
          int c2 = n0 + wc + j * 16 + mr - 1024;
          int h = c2 >> 7, d = c2 & 127;
          int gr0 = m0 + wr + i * 16 + kg * 4;
          int b = gr0 >> 11, t0 = gr0 & (T_-1);
          ushort4 o;
          o.x = f2b_hw(acc[i][j][0]); o.y = f2b_hw(acc[i][j][1]);
          o.z = f2b_hw(acc[i][j][2]); o.w = f2b_hw(acc[i][j][3]);
          size_t idx = ((size_t)(b * H_ + h) * 128 + d) * T_ + t0;
          *(ushort4*)&vtp[idx] = o;
        }
    }
  }
}

// ---------------- rope-only: fill qh/kh d=64..127 ----------------
__global__ void rope_fill(const unsigned short* __restrict__ projall,
                          unsigned short* __restrict__ qh,
                          unsigned short* __restrict__ kh){
  int row = blockIdx.x * 8 + threadIdx.y;   // (bh,t) flattened
  int j = threadIdx.x;                      // 0..31
  int bh = row >> 11;
  int t  = row & (T_ - 1);
  int b = bh >> 4, h = bh & 15;
  size_t srow = (size_t)b * T_ + t;
  const unsigned short* qp = projall + srow * 3072 + 1024 + h * 64;
  const unsigned short* kp = qp + 1024;
  float invf = exp2f(-(float)j * 0.4152410118750f);
  float f = (float)t * invf;
  float s, c;
  sincosf(f, &s, &c);
  float qx1 = b2f(qp[j]), qx2 = b2f(qp[j + 32]);
  float kx1 = b2f(kp[j]), kx2 = b2f(kp[j + 32]);
  size_t dst = ((size_t)bh * T_ + t) * 128 + 64;
  qh[dst + j]      = f2b_hw(qx1 * c - qx2 * s);
  qh[dst + j + 32] = f2b_hw(qx1 * s + qx2 * c);
  kh[dst + j]      = f2b_hw(kx1 * c - kx2 * s);
  kh[dst + j + 32] = f2b_hw(kx1 * s + kx2 * c);
}

// ---------------- causal flash attention: R5 pipeline + flat 64KB LDS + XCD-local swizzle ------
__global__ __launch_bounds__(256, 2) void attn_fwd5(
    const unsigned short* __restrict__ qh,
    const unsigned short* __restrict__ kh,
    const unsigned short* __restrict__ vt,
    unsigned short* __restrict__ ao)
{
  // flat LDS: K0 | K1 | V0 | V1, 16KB each = 64KB exact
  __shared__ __align__(16) unsigned short lds[4 * 8192];

  const int tid  = threadIdx.x;
  const int lane = tid & 63, w = tid >> 6;
  const int l31  = lane & 31, hi = lane >> 5;

  // XCD-locality swizzle: XCD r (= lin%8) handles bh in [4r, 4r+4) only.
  // qt direction alternates per 32-s group so concurrent CU slots pair (j, 15-j).
  int lin = blockIdx.x + 16 * blockIdx.y;
  int r8 = lin & 7, s = lin >> 3;
  int bh = r8 * 4 + (s >> 4);
  int j  = s & 15;
  int qt = ((s >> 5) & 1) ? (15 - j) : j;

  const int b  = bh >> 4, hd = bh & 15;
  const int q0    = qt * 128;
  const int q0w   = q0 + w * 32;
  const int qg    = q0w + l31;
  const int qmaxw = q0w + 31;
  const int nt    = 2 * qt + 2;

  const unsigned short* Qg = qh + (size_t)bh * T_ * 128;
  const unsigned short* Kg = kh + (size_t)bh * T_ * 128;
  const unsigned short* Vg = vt + (size_t)bh * 128 * T_;

  short8 qf[8];
  #pragma unroll
  for (int kc = 0; kc < 8; kc++)
    qf[kc] = *(const short8*)&Qg[(size_t)qg * 128 + kc * 16 + hi * 8];

  f32x16 accO[4];
  #pragma unroll
  for (int sb = 0; sb < 4; sb++)
    #pragma unroll
    for (int r = 0; r < 16; r++) accO[sb][r] = 0.f;

  float m = -1e30f, lsum = 0.f;
  const float SC = 0.12751743f;   // (1/sqrt(128)) * log2(e)

  // staging coordinates (per wave: 4 K rows + 4 V rows, 16B per lane)
  int krow[4], kwof[4], vrow[4], vwof[4];
  #pragma unroll
  for (int jj = 0; jj < 4; jj++){
    int r_ = (w * 4 + jj) * 4 + (lane >> 4);
    krow[jj] = r_;
    kwof[jj] = r_ * 128 + ((((lane & 15) * 16) ^ ((r_ & 7) << 4)) >> 1);
    int d_ = (w * 4 + jj) * 8 + (lane >> 3);
    vrow[jj] = d_;
    vwof[jj] = d_ * 64 + ((((lane & 7) * 16) ^ ((d_ & 7) << 4)) >> 1);
  }
  const int kcol = (lane & 15) * 8;
  const int vcol = (lane & 7) * 8;

  uint4 kst[4], vst[4];

#define REG_LOAD(kvt) do {                                                    \
    int kv0s = (kvt) * 64;                                                    \
    _Pragma("unroll")                                                         \
    for (int j_ = 0; j_ < 4; j_++) {                                          \
      kst[j_] = *(const uint4*)&Kg[(size_t)(kv0s + krow[j_]) * 128 + kcol];   \
      vst[j_] = *(const uint4*)&Vg[(size_t)vrow[j_] * T_ + kv0s + vcol];      \
    }                                                                         \
  } while (0)

#define DS_WRITE(bufi) do {                                                   \
    unsigned short* ksb_ = lds + (bufi) * 8192;                               \
    unsigned short* vsb_ = lds + 16384 + (bufi) * 8192;                       \
    _Pragma("unroll")                                                         \
    for (int j_ = 0; j_ < 4; j_++) {                                          \
      *(uint4*)&ksb_[kwof[j_]] = kst[j_];                                     \
      *(uint4*)&vsb_[vwof[j_]] = vst[j_];                                     \
    }                                                                         \
  } while (0)

  // prologue: tile0 -> LDS buf0, tile1 -> regs
  REG_LOAD(0);
  DS_WRITE(0);
  if (nt > 1) REG_LOAD(1);
  asm volatile("s_waitcnt lgkmcnt(0)" ::: "memory");
  __builtin_amdgcn_s_barrier();
  __builtin_amdgcn_sched_barrier(0);

  for (int t = 0; t < nt; t++) {
    const int cur = t & 1;
    if (t + 1 < nt) DS_WRITE(cur ^ 1);   // publish tile t+1 (regs -> LDS)
    if (t + 2 < nt) REG_LOAD(t + 2);     // issue tile t+2 (async, hides under compute)
    const int kv0 = t * 64;
    if (kv0 <= qmaxw) {
      const unsigned short* Kb = lds + cur * 8192;
      const unsigned short* Vb = lds + 16384 + cur * 8192;

      // ---- QK^T (swapped): S^T[kv][q], lane owns q col ----
      f32x16 sa0, sa1;
      #pragma unroll
      for (int r = 0; r < 16; r++) { sa0[r] = 0.f; sa1[r] = 0.f; }
      __builtin_amdgcn_s_setprio(1);
      #pragma unroll
      for (int kc = 0; kc < 8; kc++) {
        int co = (kc * 32 + hi * 16);
        int r0 = l31;
        short8 kf0 = *(const short8*)&Kb[r0 * 128 + ((co ^ ((r0 & 7) << 4)) >> 1)];
        sa0 = __builtin_amdgcn_mfma_f32_32x32x16_bf16(kf0, qf[kc], sa0, 0, 0, 0);
        int r1 = 32 + l31;
        short8 kf1 = *(const short8*)&Kb[r1 * 128 + ((co ^ ((r1 & 7) << 4)) >> 1)];
        sa1 = __builtin_amdgcn_mfma_f32_32x32x16_bf16(kf1, qf[kc], sa1, 0, 0, 0);
      }
      __builtin_amdgcn_s_setprio(0);

      // ---- lane-local softmax (exp2 domain) ----
      float p0[16], p1[16];
      float pmax = -1e30f;
      bool needMask = (kv0 + 63 > q0w);
      if (needMask) {
        #pragma unroll
        for (int r = 0; r < 16; r++) {
          int crow = (r & 3) + 8 * (r >> 2) + 4 * hi;
          float v0 = sa0[r] * SC;
          float v1 = sa1[r] * SC;
          if (kv0 + crow > qg)      v0 = -1e30f;
          if (kv0 + 32 + crow > qg) v1 = -1e30f;
          p0[r] = v0; p1[r] = v1;
          pmax = fmaxf(pmax, fmaxf(v0, v1));
        }
      } else {
        #pragma unroll
        for (int r = 0; r < 16; r++) {
          float v0 = sa0[r] * SC;
          float v1 = sa1[r] * SC;
          p0[r] = v0; p1[r] = v1;
          pmax = fmaxf(pmax, fmaxf(v0, v1));
        }
      }
      pmax = fmaxf(pmax, __shfl_xor(pmax, 32, 64));
      if (!__all(pmax <= m + 8.f)) {     // T13 defer-max
        float mn  = fmaxf(m, pmax);
        float fac = exp2f(m - mn);
        m = mn;
        lsum *= fac;
        #pragma unroll
        for (int sb = 0; sb < 4; sb++)
          #pragma unroll
          for (int r = 0; r < 16; r++) accO[sb][r] *= fac;
      }
      float ls = 0.f;
      #pragma unroll
      for (int r = 0; r < 16; r++) {
        p0[r] = exp2f(p0[r] - m);
        p1[r] = exp2f(p1[r] - m);
        ls += p0[r] + p1[r];
      }
      ls += __shfl_xor(ls, 32, 64);
      lsum += ls;

      // ---- PV: O^T[d][q] += V^T-frag x P-frag (pa via permlane32_swap, T12) ----
      #pragma unroll
      for (int kc2 = 0; kc2 < 4; kc2++) {
        unsigned A01, A23, B01, B23;
        if (kc2 == 0) { A01 = pack2(p0[0], p0[1]);  A23 = pack2(p0[2], p0[3]);
                        B01 = pack2(p0[4], p0[5]);  B23 = pack2(p0[6], p0[7]); }
        else if (kc2 == 1) { A01 = pack2(p0[8], p0[9]);   A23 = pack2(p0[10], p0[11]);
                             B01 = pack2(p0[12], p0[13]); B23 = pack2(p0[14], p0[15]); }
        else if (kc2 == 2) { A01 = pack2(p1[0], p1[1]);  A23 = pack2(p1[2], p1[3]);
                             B01 = pack2(p1[4], p1[5]);  B23 = pack2(p1[6], p1[7]); }
        else { A01 = pack2(p1[8], p1[9]);   A23 = pack2(p1[10], p1[11]);
               B01 = pack2(p1[12], p1[13]); B23 = pack2(p1[14], p1[15]); }
        asm("v_permlane32_swap_b32 %0, %1" : "+v"(A01), "+v"(B01));
        asm("v_permlane32_swap_b32 %0, %1" : "+v"(A23), "+v"(B23));
        union { unsigned u[4]; short8 v; } pk;
        pk.u[0] = A01; pk.u[1] = A23; pk.u[2] = B01; pk.u[3] = B23;
        short8 pa = pk.v;
        __builtin_amdgcn_s_setprio(1);
        #pragma unroll
        for (int sb = 0; sb < 4; sb++) {
          int d = sb * 32 + l31;
          short8 vf = *(const short8*)&Vb[d * 64 + (((kc2 * 32 + hi * 16) ^ ((d & 7) << 4)) >> 1)];
          accO[sb] = __builtin_amdgcn_mfma_f32_32x32x16_bf16(vf, pa, accO[sb], 0, 0, 0);
        }
        __builtin_amdgcn_s_setprio(0);
      }
    }
    __builtin_amdgcn_sched_barrier(0);
    asm volatile("s_waitcnt lgkmcnt(0)" ::: "memory");
    __builtin_amdgcn_s_barrier();
    __builtin_amdgcn_sched_barrier(0);
  }

  float rl = 1.0f / lsum;
  size_t orow = ((size_t)b * T_ + qg) * (H_*HD_) + hd * 128;
  #pragma unroll
  for (int sb = 0; sb < 4; sb++)
    #pragma unroll
    for (int g = 0; g < 4; g++) {
      ushort4 o;
      o.x = f2b_hw(accO[sb][4 * g + 0] * rl);
      o.y = f2b_hw(accO[sb][4 * g + 1] * rl);
      o.z = f2b_hw(accO[sb][4 * g + 2] * rl);
      o.w = f2b_hw(accO[sb][4 * g + 3] * rl);
      *(ushort4*)&ao[orow + sb * 32 + 8 * g + 4 * hi] = o;
    }
#undef REG_LOAD
#undef DS_WRITE
}

// ---------------- launcher ----------------
extern "C" void kernel_launch(void* const* d_in, const int* in_sizes, int n_in,
                              void* d_out, int out_size, void* d_ws, size_t ws_size,
                              hipStream_t stream)
{
  (void)in_sizes; (void)n_in; (void)out_size; (void)ws_size;
  const float* x        = (const float*)d_in[0];
  const float* Wq_down  = (const float*)d_in[1];
  const float* Wq_up    = (const float*)d_in[2];
  const float* Wq_rope  = (const float*)d_in[3];
  const float* Wkv_down = (const float*)d_in[4];
  const float* Wk_up    = (const float*)d_in[5];
  const float* Wv_up    = (const float*)d_in[6];
  const float* Wk_rope  = (const float*)d_in[7];
  const float* Wo       = (const float*)d_in[8];

  char* ws = (char*)d_ws;
  unsigned short* xb      = (unsigned short*)(ws + 0);          // [4096,2048] 16 MB
  unsigned short* Wdall   = (unsigned short*)(ws + 16777216);   // [3072,2048] 12 MB
  unsigned short* WquT    = (unsigned short*)(ws + 29360128);   // [1024,512]  1 MB
  unsigned short* WkcvT   = (unsigned short*)(ws + 30408704);   // [3072,512]  3 MB
  unsigned short* WoT     = (unsigned short*)(ws + 33554432);   // [2048,2048] 8 MB
  unsigned short* projall = (unsigned short*)(ws + 41943040);   // [4096,3072] 24 MB; reused as ao
  unsigned short* qh      = (unsigned short*)(ws + 67108864);   // [B,H,T,128] 16 MB
  unsigned short* kh      = (unsigned short*)(ws + 83886080);   // 16 MB
  unsigned short* vt      = (unsigned short*)(ws + 100663296);  // [B,H,128,T] 16 MB
  unsigned short* ao      = projall;

  dim3 tb(32, 8);

  cast_f32_bf16<<<(M_TOT * DM_ / 4 + 255) / 256, 256, 0, stream>>>(x, xb, M_TOT * DM_);

  TT8 tab;
  int blk = 0;
  tab.e[0] = { Wq_down,  Wdall,               DM_, QR_,     blk }; blk += (QR_/32)*(DM_/32);
  tab.e[1] = { Wkv_down, Wdall + 512*2048,    DM_, DL_,     blk }; blk += (DL_/32)*(DM_/32);
  tab.e[2] = { Wq_rope,  Wdall + 1024*2048,   DM_, H_*RD_,  blk }; blk += (H_*RD_/32)*(DM_/32);
  tab.e[3] = { Wk_rope,  Wdall + 2048*2048,   DM_, H_*RD_,  blk }; blk += (H_*RD_/32)*(DM_/32);
  tab.e[4] = { Wq_up,    WquT,                QR_, H_*CD_,  blk }; blk += (H_*CD_/32)*(QR_/32);
  tab.e[5] = { Wk_up,    WkcvT,               DL_, H_*CD_,  blk }; blk += (H_*CD_/32)*(DL_/32);
  tab.e[6] = { Wv_up,    WkcvT + 1024*512,    DL_, H_*HD_,  blk }; blk += (H_*HD_/32)*(DL_/32);
  tab.e[7] = { Wo,       WoT,                 H_*HD_, DM_,  blk }; blk += (DM_/32)*(H_*HD_/32);
  transpose_cast8<<<blk, tb, 0, stream>>>(tab);

  gemm_bt<0><<<dim3(3072/128, M_TOT/128), 256, 0, stream>>>(xb, DM_, Wdall, projall, nullptr, 3072, 3072, DM_);
  gemm_bt<2><<<dim3(1024/128, M_TOT/128), 256, 0, stream>>>(projall, 3072, WquT, qh, nullptr, 0, 1024, QR_);
  gemm_bt<3><<<dim3(3072/128, M_TOT/128), 256, 0, stream>>>(projall + 512, 3072, WkcvT, kh, vt, 0, 3072, DL_);
  rope_fill<<<dim3(B_*H_*T_/8), dim3(32, 8), 0, stream>>>(projall, qh, kh);

  attn_fwd5<<<dim3(16, 32), 256, 0, stream>>>(qh, kh, vt, ao);

  gemm_bt<1><<<dim3(DM_/128, M_TOT/128), 256, 0, stream>>>(ao, 2048, WoT, d_out, nullptr, DM_, DM_, H_*HD_);
}